// Round 1
// baseline (2225.012 us; speedup 1.0000x reference)
//
#include <hip/hip_runtime.h>

// LSTM (B=512, T=1024, I=64, H=128) + FC(128->256->1), all fp32.
// Persistent fused kernel: 256 blocks x 512 threads, 1 block/CU.
// Each block owns BCHUNK=2 batch rows for the whole T loop (batch rows are
// independent -> no grid sync ever). Thread g holds gate row g's weights
// (W_ih[g,:64] + W_hh[g,:128] = 192 VGPRs). h/x broadcast via LDS.

#define T_STEPS 1024
#define ISZ 64
#define HSZ 128
#define G4 512
#define BCHUNK 2
#define NTH 512

__device__ __forceinline__ float fast_sigmoid(float x) {
    // 1/(1+e^-x): e^x overflow -> 1/(1+inf)=0, underflow -> 1. No NaN.
    return 1.0f / (1.0f + __expf(-x));
}

__device__ __forceinline__ float fast_tanh(float x) {
    // (e^2x - 1)/(e^2x + 1): exact near 0 (no cancellation), clamp avoids inf/inf.
    float xc = fminf(fmaxf(x, -15.0f), 15.0f);
    float u = __expf(2.0f * xc);
    return (u - 1.0f) / (u + 1.0f);
}

__global__ __launch_bounds__(NTH, 2)  // 2 waves/EU -> VGPR cap 256 (need ~220)
void lstm_fused_kernel(const float* __restrict__ x,
                       const float* __restrict__ W_ih,
                       const float* __restrict__ W_hh,
                       const float* __restrict__ b_ih,
                       const float* __restrict__ b_hh,
                       const float* __restrict__ W1,
                       const float* __restrict__ b1,
                       const float* __restrict__ W2,
                       const float* __restrict__ b2,
                       float* __restrict__ out)
{
    __shared__ __align__(16) float xbuf[2][BCHUNK][ISZ];  // double-buffered x_t
    __shared__ __align__(16) float hbuf[BCHUNK][HSZ];
    __shared__ __align__(16) float gbuf[BCHUNK][G4];      // activated gates
    __shared__ float red[BCHUNK][4];

    const int tid = threadIdx.x;
    const int b0 = blockIdx.x * BCHUNK;

    // ---- per-thread gate-row weights -> registers (one-time, L2/L3 cached) ----
    float wih[ISZ];
    float whh[HSZ];
    {
        const float4* p = reinterpret_cast<const float4*>(W_ih + (size_t)tid * ISZ);
        #pragma unroll
        for (int k = 0; k < ISZ / 4; ++k) {
            float4 v = p[k];
            wih[4*k] = v.x; wih[4*k+1] = v.y; wih[4*k+2] = v.z; wih[4*k+3] = v.w;
        }
    }
    {
        const float4* p = reinterpret_cast<const float4*>(W_hh + (size_t)tid * HSZ);
        #pragma unroll
        for (int k = 0; k < HSZ / 4; ++k) {
            float4 v = p[k];
            whh[4*k] = v.x; whh[4*k+1] = v.y; whh[4*k+2] = v.z; whh[4*k+3] = v.w;
        }
    }
    const float bias = b_ih[tid] + b_hh[tid];

    // ---- init state: h=0 in LDS, c=0 in regs of threads 0..127 ----
    if (tid < BCHUNK * HSZ) hbuf[tid >> 7][tid & 127] = 0.0f;
    float c0 = 0.0f, c1 = 0.0f;

    // preload x(t=0) into buffer 0 (threads 128..255, wave-uniform group)
    if (tid >= 128 && tid < 128 + BCHUNK * ISZ) {
        int l = tid - 128;
        xbuf[0][l >> 6][l & 63] =
            x[((size_t)(b0 + (l >> 6)) * T_STEPS + 0) * ISZ + (l & 63)];
    }
    __syncthreads();

    const int gsel = tid >> 7;  // 0=i 1=f 2=g~ 3=o  (PyTorch gate order)

    for (int t = 0; t < T_STEPS; ++t) {
        const int cur = t & 1;
        const int nxt = cur ^ 1;

        // issue x(t+1) prefetch early; consumed (stored to LDS) in phase C
        float xpre = 0.0f;
        const bool pf = (tid >= 128) && (tid < 256) && (t + 1 < T_STEPS);
        if (pf) {
            int l = tid - 128;
            xpre = x[((size_t)(b0 + (l >> 6)) * T_STEPS + (t + 1)) * ISZ + (l & 63)];
        }

        // ---- phase A: gate pre-activations (dense FMA, LDS broadcast reads) ----
        float a0 = bias, a1 = bias;
        {
            const float4* xr0 = reinterpret_cast<const float4*>(xbuf[cur][0]);
            const float4* xr1 = reinterpret_cast<const float4*>(xbuf[cur][1]);
            #pragma unroll
            for (int k = 0; k < ISZ / 4; ++k) {
                float4 u = xr0[k];
                float4 v = xr1[k];
                a0 = fmaf(wih[4*k  ], u.x, a0);
                a0 = fmaf(wih[4*k+1], u.y, a0);
                a0 = fmaf(wih[4*k+2], u.z, a0);
                a0 = fmaf(wih[4*k+3], u.w, a0);
                a1 = fmaf(wih[4*k  ], v.x, a1);
                a1 = fmaf(wih[4*k+1], v.y, a1);
                a1 = fmaf(wih[4*k+2], v.z, a1);
                a1 = fmaf(wih[4*k+3], v.w, a1);
            }
            const float4* hr0 = reinterpret_cast<const float4*>(hbuf[0]);
            const float4* hr1 = reinterpret_cast<const float4*>(hbuf[1]);
            #pragma unroll
            for (int k = 0; k < HSZ / 4; ++k) {
                float4 u = hr0[k];
                float4 v = hr1[k];
                a0 = fmaf(whh[4*k  ], u.x, a0);
                a0 = fmaf(whh[4*k+1], u.y, a0);
                a0 = fmaf(whh[4*k+2], u.z, a0);
                a0 = fmaf(whh[4*k+3], u.w, a0);
                a1 = fmaf(whh[4*k  ], v.x, a1);
                a1 = fmaf(whh[4*k+1], v.y, a1);
                a1 = fmaf(whh[4*k+2], v.z, a1);
                a1 = fmaf(whh[4*k+3], v.w, a1);
            }
        }

        // activations (branch is wave-uniform: 128-thread groups = 2 waves each)
        float v0, v1;
        if (gsel == 2) { v0 = fast_tanh(a0);    v1 = fast_tanh(a1);    }
        else           { v0 = fast_sigmoid(a0); v1 = fast_sigmoid(a1); }
        gbuf[0][tid] = v0;
        gbuf[1][tid] = v1;
        __syncthreads();

        // ---- phase C: c/h update (threads 0..127) + x-prefetch store (128..255) ----
        if (tid < HSZ) {
            {
                float ig = gbuf[0][tid];
                float fg = gbuf[0][tid + 128];
                float gg = gbuf[0][tid + 256];
                float og = gbuf[0][tid + 384];
                c0 = fmaf(fg, c0, ig * gg);
                hbuf[0][tid] = og * fast_tanh(c0);
            }
            {
                float ig = gbuf[1][tid];
                float fg = gbuf[1][tid + 128];
                float gg = gbuf[1][tid + 256];
                float og = gbuf[1][tid + 384];
                c1 = fmaf(fg, c1, ig * gg);
                hbuf[1][tid] = og * fast_tanh(c1);
            }
        } else if (pf) {
            int l = tid - 128;
            xbuf[nxt][l >> 6][l & 63] = xpre;
        }
        __syncthreads();
    }

    // ---- FC head: out[b] = W2 . (W1 h + b1) + b2 (fused, per-block) ----
    {
        const int b = tid >> 8;    // threads 0..255 -> row b0, 256..511 -> row b0+1
        const int m = tid & 255;
        const float4* w1r = reinterpret_cast<const float4*>(W1 + (size_t)m * HSZ);
        const float4* hr = reinterpret_cast<const float4*>(hbuf[b]);
        float acc = 0.0f;
        #pragma unroll
        for (int k = 0; k < HSZ / 4; ++k) {
            float4 w = w1r[k];
            float4 h = hr[k];
            acc = fmaf(w.x, h.x, acc);
            acc = fmaf(w.y, h.y, acc);
            acc = fmaf(w.z, h.z, acc);
            acc = fmaf(w.w, h.w, acc);
        }
        float z = (acc + b1[m]) * W2[m];
        #pragma unroll
        for (int off = 32; off >= 1; off >>= 1)
            z += __shfl_down(z, off, 64);
        if ((tid & 63) == 0) red[b][(tid >> 6) & 3] = z;
    }
    __syncthreads();
    if (tid == 0)   out[b0]     = red[0][0] + red[0][1] + red[0][2] + red[0][3] + b2[0];
    if (tid == 256) out[b0 + 1] = red[1][0] + red[1][1] + red[1][2] + red[1][3] + b2[0];
}

extern "C" void kernel_launch(void* const* d_in, const int* in_sizes, int n_in,
                              void* d_out, int out_size, void* d_ws, size_t ws_size,
                              hipStream_t stream) {
    const float* x    = (const float*)d_in[0];
    const float* W_ih = (const float*)d_in[1];
    const float* W_hh = (const float*)d_in[2];
    const float* b_ih = (const float*)d_in[3];
    const float* b_hh = (const float*)d_in[4];
    const float* W1   = (const float*)d_in[5];
    const float* b1   = (const float*)d_in[6];
    const float* W2   = (const float*)d_in[7];
    const float* b2   = (const float*)d_in[8];
    float* out = (float*)d_out;

    lstm_fused_kernel<<<dim3(512 / BCHUNK), dim3(NTH), 0, stream>>>(
        x, W_ih, W_hh, b_ih, b_hh, W1, b1, W2, b2, out);
}